// Round 19
// baseline (59.583 us; speedup 1.0000x reference)
//
#include <hip/hip_runtime.h>

typedef __attribute__((ext_vector_type(8))) short s8v;
typedef __attribute__((ext_vector_type(4))) short s4v;
typedef __attribute__((ext_vector_type(4))) float fx4;
typedef __attribute__((ext_vector_type(4))) unsigned int u32x4;
typedef __attribute__((ext_vector_type(2))) unsigned int u32x2;
typedef unsigned short u16;
typedef unsigned int u32;
typedef unsigned char u8;

#define QK_SCALE 0.1803368801111204f  /* 0.125 * log2(e) */

#if __has_builtin(__builtin_amdgcn_exp2f)
#define EXP2(x) __builtin_amdgcn_exp2f(x)
#else
#define EXP2(x) exp2f(x)
#endif

static __device__ __forceinline__ u16 f2bf(float f) {
    u32 u = __float_as_uint(f);
    u += 0x7fffu + ((u >> 16) & 1u);
    return (u16)(u >> 16);
}
static __device__ __forceinline__ float bf2f(u16 h) {
    return __uint_as_float(((u32)h) << 16);
}
// truncate-pack two f32 -> two bf16 in one v_perm (softmax cancels the common bias)
static __device__ __forceinline__ int packtrunc(float a, float b) {
    return (int)__builtin_amdgcn_perm(__float_as_uint(b), __float_as_uint(a), 0x07060302u);
}

static __device__ __forceinline__ fx4 mfma16(s4v a, s4v b, fx4 c) {
#if __has_builtin(__builtin_amdgcn_mfma_f32_16x16x16bf16_1k)
    return __builtin_amdgcn_mfma_f32_16x16x16bf16_1k(a, b, c, 0, 0, 0);
#elif __has_builtin(__builtin_amdgcn_mfma_f32_16x16x16_bf16)
    return __builtin_amdgcn_mfma_f32_16x16x16_bf16(a, b, c, 0, 0, 0);
#else
    asm("v_mfma_f32_16x16x16_bf16 %0, %1, %2, %3" : "=v"(c) : "v"(a), "v"(b), "v"(c));
    return c;
#endif
}

// ---------------- K1: qkv proj (4 rows/block, 2048 blocks), COALESCED stores ----------------
// Compute phase unchanged; acc -> LDS transpose; store phase re-maps threads to output
// rows: Qh 32B/row (hi16|lo16), Kh 16B/key (hi-only), Vt 8B chunks. Same f2bf values.
__global__ __launch_bounds__(192) void qkv_proj_kernel(
    const float* __restrict__ X, const float* __restrict__ W,
    const float* __restrict__ bias,
    u16* __restrict__ Qh, u16* __restrict__ Kh, u16* __restrict__ Vt,
    u32* __restrict__ VtBoth)
{
    {
        const int gt = blockIdx.x * 192 + threadIdx.x;
        if (gt < 65536) {   // [buf2][bh32][kg128] regions x 8 ones-words
            const int region = gt >> 3, word = gt & 7;
            VtBoth[region * 128 + 64 + word] = 0x3f803f80u;
        }
    }
    __shared__ __align__(16) float xsT[64 * 8];    // [k][r], stride 8
    __shared__ __align__(16) float accL[192 * 4];  // [col][r], 3KB
    const int row0 = blockIdx.x * 4;
    const int t = threadIdx.x;
    if (t < 64) {
        float4 xv;
        xv.x = X[(size_t)(row0 + 0) * 64 + t];
        xv.y = X[(size_t)(row0 + 1) * 64 + t];
        xv.z = X[(size_t)(row0 + 2) * 64 + t];
        xv.w = X[(size_t)(row0 + 3) * 64 + t];
        *(float4*)&xsT[t * 8] = xv;
    }
    __syncthreads();
    const float bj = bias[t];
    float a0 = bj, a1 = bj, a2 = bj, a3 = bj;
    #pragma unroll 8
    for (int k = 0; k < 64; ++k) {
        const float w = W[k * 192 + t];
        const float4 x = *(const float4*)&xsT[k * 8];
        a0 = fmaf(x.x, w, a0);
        a1 = fmaf(x.y, w, a1);
        a2 = fmaf(x.z, w, a2);
        a3 = fmaf(x.w, w, a3);
    }
    {
        const float4 av = {a0, a1, a2, a3};
        *(float4*)&accL[t * 4] = av;
    }
    __syncthreads();

    const int bi = row0 >> 11, i0 = row0 & 2047;
    if (t < 32) {
        // Q: (r,h) pair -> 32B contiguous row (hi 16B | lo 16B)
        const int r = t >> 3, h = t & 7;
        const int bh = bi * 8 + h, i = i0 + r;
        u32x4 hi, lo;
        #pragma unroll
        for (int dp = 0; dp < 4; ++dp) {
            const float q0 = accL[(h * 8 + 2 * dp) * 4 + r] * QK_SCALE;
            const float q1 = accL[(h * 8 + 2 * dp + 1) * 4 + r] * QK_SCALE;
            const u16 h0 = f2bf(q0), h1 = f2bf(q1);
            const u16 l0 = f2bf(q0 - bf2f(h0)), l1 = f2bf(q1 - bf2f(h1));
            hi[dp] = (u32)h0 | ((u32)h1 << 16);
            lo[dp] = (u32)l0 | ((u32)l1 << 16);
        }
        u32* qp = (u32*)(Qh + ((size_t)(bh * 2048 + i)) * 16);
        *(u32x4*)qp = hi;
        *(u32x4*)(qp + 4) = lo;
    } else if (t < 64) {
        // K: (r,h) pair -> 16B contiguous row (hi-only)
        const int p = t - 32;
        const int r = p >> 3, h = p & 7;
        const int bh = bi * 8 + h, i = i0 + r;
        u32x4 w4;
        #pragma unroll
        for (int dp = 0; dp < 4; ++dp) {
            const float v0 = accL[(64 + h * 8 + 2 * dp) * 4 + r];
            const float v1 = accL[(64 + h * 8 + 2 * dp + 1) * 4 + r];
            w4[dp] = (u32)f2bf(v0) | ((u32)f2bf(v1) << 16);
        }
        *(u32x4*)(Kh + ((size_t)(bh * 128 + (i >> 4)) * 16 + (i & 15)) * 8) = w4;
    } else if (t < 128) {
        // V: (h,d) -> 8B chunk (4 consecutive keys), kr 4-aligned
        const int p = t - 64;
        const int h = p >> 3, d = p & 7;
        const int bh = bi * 8 + h;
        const int kg = i0 >> 4, kr = i0 & 15;
        const float v0 = accL[(128 + h * 8 + d) * 4 + 0];
        const float v1 = accL[(128 + h * 8 + d) * 4 + 1];
        const float v2 = accL[(128 + h * 8 + d) * 4 + 2];
        const float v3 = accL[(128 + h * 8 + d) * 4 + 3];
        u32x2 w2;
        w2[0] = (u32)f2bf(v0) | ((u32)f2bf(v1) << 16);
        w2[1] = (u32)f2bf(v2) | ((u32)f2bf(v3) << 16);
        *(u32x2*)(Vt + ((size_t)(bh * 128 + kg) * 16 + d) * 16 + kr) = w2;
    }
}

// ---------------- MFMA attention v14 (R18-proven): K hi-only, QK = 16x16x16 ----------------
// grid (bh=32, qt=64), x=bh fastest (XCD-L2-local). 8 blocks/CU, VGPR<=64 (lb 256,8).
// Block: 32 q x 2048 keys. Wave w: keys [w*512,(w+1)*512), 32 segs, 2-seg prefetch.
// QK 16x16x16: A lane(key=ql, g) = Khi d[4(g&1)..+3]; B = [qhi03,qhi47,qlo03,qlo47][g]
//   -> S = Khi·(Qhi+Qlo). C: col=q=l&15, row=key=4g+r. P=exp2 -> packtrunc -> B-frag.
// PV + ones-row denominator; ds_bpermute broadcast; normalized write in-kernel.
__global__ __launch_bounds__(256, 8) void attn_mfma14_kernel(
    const u16* __restrict__ Qh, const u8* __restrict__ Khb,
    const u8* __restrict__ Vtb, float* __restrict__ M)
{
    __shared__ __align__(16) float Lr[4][2][64][4];   // [wave][qg][lane][4] = 8KB
    const int bh = blockIdx.x, qt = blockIdx.y;
    const int tid = threadIdx.x, w = tid >> 6, l = tid & 63;
    const int g = l >> 4, ql = l & 15;

    s4v bq[2];
    #pragma unroll
    for (int qg = 0; qg < 2; ++qg)
        bq[qg] = *(const s4v*)(Qh + ((size_t)(bh * 2048 + qt * 32 + qg * 16 + ql)) * 16
                               + g * 4);

    const u8* kb = Khb + (size_t)bh * 32768 + w * 8192 + ql * 16 + (g & 1) * 8;
    const u8* vb = Vtb + (size_t)bh * 65536 + w * 16384 + ql * 32 + g * 8;

    fx4 acc[2];
    acc[0] = fx4{0.f, 0.f, 0.f, 0.f};
    acc[1] = fx4{0.f, 0.f, 0.f, 0.f};
    const fx4 zf = {0.f, 0.f, 0.f, 0.f};

    s4v k0 = *(const s4v*)(kb);
    s4v k1 = *(const s4v*)(kb + 256);
    s4v v0 = *(const s4v*)(vb);
    s4v v1 = *(const s4v*)(vb + 512);

#define PROCESS(KA, VA)                                                         \
    {                                                                           \
        _Pragma("unroll")                                                       \
        for (int qg = 0; qg < 2; ++qg) {                                        \
            fx4 s = mfma16(KA, bq[qg], zf);                                     \
            union { int i2[2]; s4v v; } bp;                                     \
            bp.i2[0] = packtrunc(EXP2(s[0]), EXP2(s[1]));                       \
            bp.i2[1] = packtrunc(EXP2(s[2]), EXP2(s[3]));                       \
            acc[qg] = mfma16(VA, bp.v, acc[qg]);                                \
        }                                                                       \
    }

    #pragma unroll 1
    for (int it = 0; it < 16; ++it) {
        const s4v k2 = *(const s4v*)(kb + 512);
        const s4v v2 = *(const s4v*)(vb + 1024);
        const s4v k3 = *(const s4v*)(kb + 768);
        const s4v v3 = *(const s4v*)(vb + 1536);
        kb += 512; vb += 1024;
        __builtin_amdgcn_s_setprio(1);
        PROCESS(k0, v0);
        PROCESS(k1, v1);
        __builtin_amdgcn_s_setprio(0);
        k0 = k2; v0 = v2; k1 = k3; v1 = v3;
    }
#undef PROCESS

    // cross-wave reduction over key-quarters
    *(fx4*)&Lr[w][0][l][0] = acc[0];
    *(fx4*)&Lr[w][1][l][0] = acc[1];
    __syncthreads();

    if (w < 2) {                                   // wave w finalizes qg=w
        fx4 fin = {0.f, 0.f, 0.f, 0.f};
        #pragma unroll
        for (int wp = 0; wp < 4; ++wp) {
            const fx4 v = *(const fx4*)&Lr[wp][w][l][0];
            fin[0] += v[0]; fin[1] += v[1]; fin[2] += v[2]; fin[3] += v[3];
        }
        // denominator = O^T row 8 = lanes 32..47 (g==2, reg 0), col q
        const int lv_i = __builtin_amdgcn_ds_bpermute((32 + ql) * 4, __float_as_int(fin[0]));
        const float inv = 1.0f / __int_as_float(lv_i);
        if (g < 2) {
            const int qglob = qt * 32 + w * 16 + ql;
            const int b = bh >> 3, h = bh & 7;
            const float4 o = {fin[0] * inv, fin[1] * inv, fin[2] * inv, fin[3] * inv};
            *(float4*)(M + ((size_t)(b * 2048 + qglob)) * 64 + h * 8 + g * 4) = o;
        }
    }
}

// ---------------- proj64 (4 rows/block): mode 0 coalesced via LDS transpose ----------------
// A 4-row block maps to ONE bh and 32 consecutive keys: Q1 rows 32B, K1 16B/key,
// Vt1 full 32B rows. mode 1 -> plain f32 out (already coalesced).
// q1 reshape: p-row rr, col c -> bh=bi*8+(rr>>8), key=(rr&255)*8+(c>>3), d=c&7
__global__ __launch_bounds__(64) void proj64_kernel(
    const float* __restrict__ X, const float* __restrict__ W,
    const float* __restrict__ bias,
    u16* __restrict__ Qh, u16* __restrict__ Kh, u16* __restrict__ Vt,
    float* __restrict__ Out, int mode)
{
    __shared__ __align__(16) float xsT[64 * 8];   // [k][r], stride 8
    __shared__ __align__(16) float accL[64 * 4];  // [col][r], 1KB
    const int row0 = blockIdx.x * 4;
    const int c = threadIdx.x;
    {
        float4 xv;
        xv.x = X[(size_t)(row0 + 0) * 64 + c];
        xv.y = X[(size_t)(row0 + 1) * 64 + c];
        xv.z = X[(size_t)(row0 + 2) * 64 + c];
        xv.w = X[(size_t)(row0 + 3) * 64 + c];
        *(float4*)&xsT[c * 8] = xv;
    }
    __syncthreads();
    const float bc = bias[c];
    float a0 = bc, a1 = bc, a2 = bc, a3 = bc;
    #pragma unroll 8
    for (int k = 0; k < 64; ++k) {
        const float w = W[k * 64 + c];
        const float4 x = *(const float4*)&xsT[k * 8];
        a0 = fmaf(x.x, w, a0);
        a1 = fmaf(x.y, w, a1);
        a2 = fmaf(x.z, w, a2);
        a3 = fmaf(x.w, w, a3);
    }
    if (mode == 0) {
        {
            const float4 av = {a0, a1, a2, a3};
            *(float4*)&accL[c * 4] = av;
        }
        __syncthreads();
        const int bi = row0 >> 11, rr0 = row0 & 2047;
        const int bh = bi * 8 + (rr0 >> 8);
        const int keybase = (rr0 & 255) * 8;
        if (c < 32) {
            // Q1: key kk -> 32B row (hi 16B | lo 16B)
            const int kk = c, key = keybase + kk;
            const int r = kk >> 3, chi = kk & 7;
            u32x4 hi, lo;
            #pragma unroll
            for (int dp = 0; dp < 4; ++dp) {
                const float q0 = accL[(chi * 8 + 2 * dp) * 4 + r] * QK_SCALE;
                const float q1 = accL[(chi * 8 + 2 * dp + 1) * 4 + r] * QK_SCALE;
                const u16 h0 = f2bf(q0), h1 = f2bf(q1);
                const u16 l0 = f2bf(q0 - bf2f(h0)), l1 = f2bf(q1 - bf2f(h1));
                hi[dp] = (u32)h0 | ((u32)h1 << 16);
                lo[dp] = (u32)l0 | ((u32)l1 << 16);
            }
            u32* qp = (u32*)(Qh + ((size_t)(bh * 2048 + key)) * 16);
            *(u32x4*)qp = hi;
            *(u32x4*)(qp + 4) = lo;
        } else {
            // K1: key kk -> 16B row (hi-only)
            const int kk = c - 32, key = keybase + kk;
            const int r = kk >> 3, chi = kk & 7;
            u32x4 w4;
            #pragma unroll
            for (int dp = 0; dp < 4; ++dp) {
                const float v0 = accL[(chi * 8 + 2 * dp) * 4 + r];
                const float v1 = accL[(chi * 8 + 2 * dp + 1) * 4 + r];
                w4[dp] = (u32)f2bf(v0) | ((u32)f2bf(v1) << 16);
            }
            *(u32x4*)(Kh + ((size_t)(bh * 128 + (key >> 4)) * 16 + (key & 15)) * 8) = w4;
        }
        if (c < 16) {
            // V1: (kgi,d) -> full 32B Vt row (16 keys)
            const int kgi = c >> 3, d = c & 7;
            const int kg = (keybase >> 4) + kgi;
            u32 w8[8];
            #pragma unroll
            for (int kp = 0; kp < 8; ++kp) {
                const int kkA = kgi * 16 + 2 * kp, kkB = kkA + 1;
                const float vA = accL[((kkA & 7) * 8 + d) * 4 + (kkA >> 3)];
                const float vB = accL[((kkB & 7) * 8 + d) * 4 + (kkB >> 3)];
                w8[kp] = (u32)f2bf(vA) | ((u32)f2bf(vB) << 16);
            }
            u32* vp = (u32*)(Vt + ((size_t)(bh * 128 + kg) * 16 + d) * 16);
            *(u32x4*)vp = *(u32x4*)&w8[0];
            *(u32x4*)(vp + 4) = *(u32x4*)&w8[4];
        }
    } else {
        const float accv[4] = {a0, a1, a2, a3};
        #pragma unroll
        for (int r = 0; r < 4; ++r)
            Out[(size_t)(row0 + r) * 64 + c] = accv[r];
    }
}

extern "C" void kernel_launch(void* const* d_in, const int* in_sizes, int n_in,
                              void* d_out, int out_size, void* d_ws, size_t ws_size,
                              hipStream_t stream) {
    const float* x    = (const float*)d_in[0];
    const float* Wqkv = (const float*)d_in[1];
    const float* bqkv = (const float*)d_in[2];
    const float* W1   = (const float*)d_in[3];
    const float* b1   = (const float*)d_in[4];
    float* out = (float*)d_out;
    u8* w8 = (u8*)d_ws;

    // byte layout (14 MiB reserved; Kh 1 MiB each, slots kept at 2 MiB)
    u16*   Qh0  = (u16*)(w8);                       // 2 MiB
    u16*   Kh0  = (u16*)(w8 + (2u << 20));          // 1 MiB used
    u16*   Vt0  = (u16*)(w8 + (4u << 20));          // 2 MiB
    u16*   Vt1  = (u16*)(w8 + (6u << 20));          // 2 MiB (adjacent to Vt0 for init)
    u16*   Qh1  = (u16*)(w8 + (8u << 20));          // 2 MiB
    u16*   Kh1  = (u16*)(w8 + (10u << 20));         // 1 MiB used
    float* M1   = (float*)(w8 + (12u << 20));       // 2 MiB
    float* M2   = (float*)(w8);                     // overlays Qh0 (dead by then)

    qkv_proj_kernel<<<2048, 192, 0, stream>>>(x, Wqkv, bqkv, Qh0, Kh0, Vt0, (u32*)Vt0);
    attn_mfma14_kernel<<<dim3(32, 64), 256, 0, stream>>>(Qh0, (const u8*)Kh0, (const u8*)Vt0, M1);
    proj64_kernel<<<2048, 64, 0, stream>>>(M1, W1, b1, Qh1, Kh1, Vt1, nullptr, 0);
    attn_mfma14_kernel<<<dim3(32, 64), 256, 0, stream>>>(Qh1, (const u8*)Kh1, (const u8*)Vt1, M2);
    proj64_kernel<<<2048, 64, 0, stream>>>(M2, W1, b1, nullptr, nullptr, nullptr, out, 1);
}